// Round 2
// baseline (283.389 us; speedup 1.0000x reference)
//
#include <hip/hip_runtime.h>

// YOLO loss, B=32 W=64 H=64 A=5 C=80 M=50
#define Bb 32
#define Ww 64
#define Hh 64
#define Aa 5
#define Cc 80
#define Mm 50
#define IOU_THR 0.5f
#define ANCHOR_TRAIN_ITERS 12800

__global__ void zero_out_kernel(float* out) { out[0] = 0.0f; }

__launch_bounds__(256)
__global__ void yolo_loss_kernel(const int* __restrict__ iter_num,
                                 const float* __restrict__ cls_score,
                                 const float* __restrict__ pred_object,
                                 const float* __restrict__ true_label,
                                 const float* __restrict__ true_object,
                                 const float* __restrict__ anchors,
                                 float* __restrict__ out)
{
    const int tid  = threadIdx.x;
    const int gidx = blockIdx.x * 256 + tid;   // flat (b,w,h,a) index
    const int per_b = Ww * Hh * Aa;            // 20480; 256 | 20480, so each block is within one b
    const int b   = gidx / per_b;
    int rem       = gidx - b * per_b;
    const int w   = rem / (Hh * Aa);
    rem          -= w * (Hh * Aa);
    const int h   = rem / Aa;
    const int a   = rem - h * Aa;

    // Stage this batch's GT boxes + anchors in LDS (tiny)
    __shared__ float s_box[Mm][4];
    __shared__ int   s_ci[Mm];
    __shared__ int   s_cj[Mm];
    __shared__ float s_anch[Aa * 2];
    if (tid < Mm) {
        const float* t = true_object + ((size_t)b * Mm + tid) * 4;
        float x = t[0], y = t[1];
        s_box[tid][0] = x;
        s_box[tid][1] = y;
        s_box[tid][2] = t[2];
        s_box[tid][3] = t[3];
        int ci = (int)floorf(x); ci = min(max(ci, 0), Ww - 1);
        int cj = (int)floorf(y); cj = min(max(cj, 0), Hh - 1);
        s_ci[tid] = ci;
        s_cj[tid] = cj;
    }
    if (tid < Aa * 2) s_anch[tid] = anchors[tid];
    __syncthreads();

    // Decode this cell/anchor's prediction
    const float aw = s_anch[a * 2 + 0];
    const float ah = s_anch[a * 2 + 1];
    const float* po = pred_object + (size_t)gidx * 5;
    const float tx = po[0], ty = po[1], tw = po[2], th = po[3], tc = po[4];
    const float conf = 1.0f / (1.0f + expf(-tc));
    const float px = 1.0f / (1.0f + expf(-tx)) + (float)w;   // grid[w,h] = (w,h)
    const float py = 1.0f / (1.0f + expf(-ty)) + (float)h;
    const float ew = expf(tw) * aw;
    const float eh = expf(th) * ah;

    // Winner GT box at this cell: duplicate scatters -> last m wins
    int win = -1;
    for (int m = 0; m < Mm; ++m) {
        if (s_ci[m] == w && s_cj[m] == h) win = m;
    }

    float acc = 0.0f;   // sum of all per-element loss contributions (divisors folded in)
    float obj = 0.0f;
    if (win >= 0) {
        const float ttw = s_box[win][2], tth = s_box[win][3];
        const float inter = fminf(ttw, aw) * fminf(tth, ah);
        const float uni   = ttw * tth + aw * ah - inter;
        const float iou   = inter / uni;
        if (iou > IOU_THR) {
            obj = 1.0f;
            // obj_loss: mean over N elems -> per-elem term
            const float dco = conf - iou;
            acc += 5.0f * 0.5f * dco * dco;
            // prior_loss: mean over 2N
            const float np_ = (iter_num[0] < ANCHOR_TRAIN_ITERS) ? 1.0f : 0.0f;
            const float dw = ew - aw, dh = eh - ah;
            acc += np_ * 5.0f * 0.5f * (dw * dw + dh * dh) * 0.5f;
            // true_loss: mean over 4N
            const float ttx = s_box[win][0], tty = s_box[win][1];
            const float d0 = px - ttx, d1 = py - tty, d2 = ew - ttw, d3 = eh - tth;
            acc += 5.0f * 0.5f * (d0 * d0 + d1 * d1 + d2 * d2 + d3 * d3) * 0.25f;
            // score_loss: mean over C*N  (cls_score touched ONLY here -> sparse read)
            // Both rows are 80 floats = 320 B aligned -> float4 loads.
            const float4* cs4 = reinterpret_cast<const float4*>(cls_score + (size_t)gidx * Cc);
            const float4* tl4 = reinterpret_cast<const float4*>(true_label + ((size_t)b * Mm + win) * Cc);
            float ssum = 0.0f;
            #pragma unroll
            for (int c = 0; c < Cc / 4; ++c) {
                const float4 cv = cs4[c];
                const float4 tv = tl4[c];
                const float e0 = cv.x - tv.x, e1 = cv.y - tv.y;
                const float e2 = cv.z - tv.z, e3 = cv.w - tv.w;
                ssum += e0 * e0 + e1 * e1 + e2 * e2 + e3 * e3;
            }
            acc += 5.0f * 0.5f * ssum * (1.0f / (float)Cc);
        }
    }
    // noobj_loss: every cell/anchor
    acc += 0.5f * (1.0f - obj) * 0.5f * conf * conf;

    const float invN = 1.0f / ((float)Bb * (float)Ww * (float)Hh * (float)Aa);
    acc *= invN * 0.25f;   // all five means share divisor N; final /4

    // Block reduction: wave64 shuffle, then cross-wave via LDS, one atomic per block
    #pragma unroll
    for (int off = 32; off > 0; off >>= 1)
        acc += __shfl_down(acc, off, 64);
    __shared__ float s_part[4];
    if ((tid & 63) == 0) s_part[tid >> 6] = acc;
    __syncthreads();
    if (tid == 0)
        atomicAdd(out, s_part[0] + s_part[1] + s_part[2] + s_part[3]);
}

extern "C" void kernel_launch(void* const* d_in, const int* in_sizes, int n_in,
                              void* d_out, int out_size, void* d_ws, size_t ws_size,
                              hipStream_t stream) {
    const int*   iter_num    = (const int*)  d_in[0];
    const float* cls_score   = (const float*)d_in[1];
    const float* pred_object = (const float*)d_in[2];
    const float* true_label  = (const float*)d_in[3];
    const float* true_object = (const float*)d_in[4];
    const float* anchors     = (const float*)d_in[5];
    float* out = (float*)d_out;

    zero_out_kernel<<<1, 1, 0, stream>>>(out);

    const int total  = Bb * Ww * Hh * Aa;       // 655360
    const int blocks = total / 256;             // 2560
    yolo_loss_kernel<<<blocks, 256, 0, stream>>>(iter_num, cls_score, pred_object,
                                                 true_label, true_object, anchors, out);
}

// Round 3
// 259.895 us; speedup vs baseline: 1.0904x; 1.0904x over previous
//
#include <hip/hip_runtime.h>

// YOLO loss, B=32 W=64 H=64 A=5 C=80 M=50
#define Bb 32
#define Ww 64
#define Hh 64
#define Aa 5
#define Cc 80
#define Mm 50
#define IOU_THR 0.5f
#define ANCHOR_TRAIN_ITERS 12800

#define NBLOCKS 2560   // (B*W*H*A)/256

__launch_bounds__(256)
__global__ void yolo_loss_kernel(const int* __restrict__ iter_num,
                                 const float* __restrict__ cls_score,
                                 const float* __restrict__ pred_object,
                                 const float* __restrict__ true_label,
                                 const float* __restrict__ true_object,
                                 const float* __restrict__ anchors,
                                 float* __restrict__ partials)
{
    const int tid  = threadIdx.x;
    const int gidx = blockIdx.x * 256 + tid;   // flat (b,w,h,a) index
    const int per_b = Ww * Hh * Aa;            // 20480; 256 | 20480, so each block is within one b
    const int b   = gidx / per_b;
    int rem       = gidx - b * per_b;
    const int w   = rem / (Hh * Aa);
    rem          -= w * (Hh * Aa);
    const int h   = rem / Aa;
    const int a   = rem - h * Aa;

    // Stage this batch's GT boxes + anchors in LDS (tiny)
    __shared__ float s_box[Mm][4];
    __shared__ int   s_ci[Mm];
    __shared__ int   s_cj[Mm];
    __shared__ float s_anch[Aa * 2];
    if (tid < Mm) {
        const float* t = true_object + ((size_t)b * Mm + tid) * 4;
        float x = t[0], y = t[1];
        s_box[tid][0] = x;
        s_box[tid][1] = y;
        s_box[tid][2] = t[2];
        s_box[tid][3] = t[3];
        int ci = (int)floorf(x); ci = min(max(ci, 0), Ww - 1);
        int cj = (int)floorf(y); cj = min(max(cj, 0), Hh - 1);
        s_ci[tid] = ci;
        s_cj[tid] = cj;
    }
    if (tid < Aa * 2) s_anch[tid] = anchors[tid];
    __syncthreads();

    // Decode this cell/anchor's prediction
    const float aw = s_anch[a * 2 + 0];
    const float ah = s_anch[a * 2 + 1];
    const float* po = pred_object + (size_t)gidx * 5;
    const float tx = po[0], ty = po[1], tw = po[2], th = po[3], tc = po[4];
    const float conf = 1.0f / (1.0f + expf(-tc));
    const float px = 1.0f / (1.0f + expf(-tx)) + (float)w;   // grid[w,h] = (w,h)
    const float py = 1.0f / (1.0f + expf(-ty)) + (float)h;
    const float ew = expf(tw) * aw;
    const float eh = expf(th) * ah;

    // Winner GT box at this cell: duplicate scatters -> last m wins
    int win = -1;
    for (int m = 0; m < Mm; ++m) {
        if (s_ci[m] == w && s_cj[m] == h) win = m;
    }

    float acc = 0.0f;   // sum of all per-element loss contributions (divisors folded in)
    float obj = 0.0f;
    if (win >= 0) {
        const float ttw = s_box[win][2], tth = s_box[win][3];
        const float inter = fminf(ttw, aw) * fminf(tth, ah);
        const float uni   = ttw * tth + aw * ah - inter;
        const float iou   = inter / uni;
        if (iou > IOU_THR) {
            obj = 1.0f;
            // obj_loss: mean over N elems -> per-elem term
            const float dco = conf - iou;
            acc += 5.0f * 0.5f * dco * dco;
            // prior_loss: mean over 2N
            const float np_ = (iter_num[0] < ANCHOR_TRAIN_ITERS) ? 1.0f : 0.0f;
            const float dw = ew - aw, dh = eh - ah;
            acc += np_ * 5.0f * 0.5f * (dw * dw + dh * dh) * 0.5f;
            // true_loss: mean over 4N
            const float ttx = s_box[win][0], tty = s_box[win][1];
            const float d0 = px - ttx, d1 = py - tty, d2 = ew - ttw, d3 = eh - tth;
            acc += 5.0f * 0.5f * (d0 * d0 + d1 * d1 + d2 * d2 + d3 * d3) * 0.25f;
            // score_loss: mean over C*N  (cls_score touched ONLY here -> sparse read)
            const float4* cs4 = reinterpret_cast<const float4*>(cls_score + (size_t)gidx * Cc);
            const float4* tl4 = reinterpret_cast<const float4*>(true_label + ((size_t)b * Mm + win) * Cc);
            float ssum = 0.0f;
            #pragma unroll
            for (int c = 0; c < Cc / 4; ++c) {
                const float4 cv = cs4[c];
                const float4 tv = tl4[c];
                const float e0 = cv.x - tv.x, e1 = cv.y - tv.y;
                const float e2 = cv.z - tv.z, e3 = cv.w - tv.w;
                ssum += e0 * e0 + e1 * e1 + e2 * e2 + e3 * e3;
            }
            acc += 5.0f * 0.5f * ssum * (1.0f / (float)Cc);
        }
    }
    // noobj_loss: every cell/anchor
    acc += 0.5f * (1.0f - obj) * 0.5f * conf * conf;

    const float invN = 1.0f / ((float)Bb * (float)Ww * (float)Hh * (float)Aa);
    acc *= invN * 0.25f;   // all five means share divisor N; final /4

    // Block reduction: wave64 shuffle, then cross-wave via LDS, one partial per block
    #pragma unroll
    for (int off = 32; off > 0; off >>= 1)
        acc += __shfl_down(acc, off, 64);
    __shared__ float s_part[4];
    if ((tid & 63) == 0) s_part[tid >> 6] = acc;
    __syncthreads();
    if (tid == 0)
        partials[blockIdx.x] = s_part[0] + s_part[1] + s_part[2] + s_part[3];
}

__launch_bounds__(256)
__global__ void reduce_kernel(const float* __restrict__ partials, float* __restrict__ out)
{
    const int tid = threadIdx.x;
    float acc = 0.0f;
    #pragma unroll
    for (int i = tid; i < NBLOCKS; i += 256)
        acc += partials[i];
    #pragma unroll
    for (int off = 32; off > 0; off >>= 1)
        acc += __shfl_down(acc, off, 64);
    __shared__ float s_part[4];
    if ((tid & 63) == 0) s_part[tid >> 6] = acc;
    __syncthreads();
    if (tid == 0)
        out[0] = s_part[0] + s_part[1] + s_part[2] + s_part[3];
}

extern "C" void kernel_launch(void* const* d_in, const int* in_sizes, int n_in,
                              void* d_out, int out_size, void* d_ws, size_t ws_size,
                              hipStream_t stream) {
    const int*   iter_num    = (const int*)  d_in[0];
    const float* cls_score   = (const float*)d_in[1];
    const float* pred_object = (const float*)d_in[2];
    const float* true_label  = (const float*)d_in[3];
    const float* true_object = (const float*)d_in[4];
    const float* anchors     = (const float*)d_in[5];
    float* out      = (float*)d_out;
    float* partials = (float*)d_ws;   // 2560 floats = 10 KB, all overwritten every call

    yolo_loss_kernel<<<NBLOCKS, 256, 0, stream>>>(iter_num, cls_score, pred_object,
                                                  true_label, true_object, anchors, partials);
    reduce_kernel<<<1, 256, 0, stream>>>(partials, out);
}

// Round 4
// 257.447 us; speedup vs baseline: 1.1008x; 1.0095x over previous
//
#include <hip/hip_runtime.h>

// YOLO loss, B=32 W=64 H=64 A=5 C=80 M=50
#define Bb 32
#define Ww 64
#define Hh 64
#define Aa 5
#define Cc 80
#define Mm 50
#define IOU_THR 0.5f
#define ANCHOR_TRAIN_ITERS 12800

#define NBLOCKS 2560   // (B*W*H*A)/256

__launch_bounds__(256)
__global__ void yolo_loss_kernel(const int* __restrict__ iter_num,
                                 const float* __restrict__ cls_score,
                                 const float* __restrict__ pred_object,
                                 const float* __restrict__ true_label,
                                 const float* __restrict__ true_object,
                                 const float* __restrict__ anchors,
                                 float* __restrict__ partials)
{
    const int tid  = threadIdx.x;
    const int gidx = blockIdx.x * 256 + tid;   // flat (b,w,h,a) index
    const int per_b = Ww * Hh * Aa;            // 20480; 256 | 20480 -> block within one b
    const int b    = gidx / per_b;
    const int cell = gidx / Aa;                // global cell index b*4096 + w*64 + h
    int rem        = gidx - b * per_b;
    const int w    = rem / (Hh * Aa);
    rem           -= w * (Hh * Aa);
    const int h    = rem / Aa;
    const int a    = rem - h * Aa;

    // Per-block winner table: block covers <=52 cells; "last m wins" == "max m wins"
    __shared__ int   s_win[56];
    __shared__ float s_anch[Aa * 2];
    const int cell0 = (blockIdx.x * 256) / Aa;
    const int ncell = (blockIdx.x * 256 + 255) / Aa - cell0 + 1;
    if (tid < ncell) s_win[tid] = -1;
    if (tid < Aa * 2) s_anch[tid] = anchors[tid];
    __syncthreads();
    if (tid < Mm) {
        const float* t = true_object + ((size_t)b * Mm + tid) * 4;
        int ci = (int)floorf(t[0]); ci = min(max(ci, 0), Ww - 1);
        int cj = (int)floorf(t[1]); cj = min(max(cj, 0), Hh - 1);
        const int bcell = b * (Ww * Hh) + ci * Hh + cj;
        if (bcell >= cell0 && bcell < cell0 + ncell)
            atomicMax(&s_win[bcell - cell0], tid);   // LDS atomic, trivial contention
    }
    __syncthreads();
    const int win = s_win[cell - cell0];   // 5 anchors/cell -> broadcast read

    // Decode this cell/anchor's prediction
    const float aw = s_anch[a * 2 + 0];
    const float ah = s_anch[a * 2 + 1];
    const float* po = pred_object + (size_t)gidx * 5;
    const float tx = po[0], ty = po[1], tw = po[2], th = po[3], tc = po[4];
    const float conf = 1.0f / (1.0f + expf(-tc));
    const float px = 1.0f / (1.0f + expf(-tx)) + (float)w;   // grid[w,h] = (w,h)
    const float py = 1.0f / (1.0f + expf(-ty)) + (float)h;
    const float ew = expf(tw) * aw;
    const float eh = expf(th) * ah;

    float acc = 0.0f;   // per-element loss contributions (divisors folded in)
    float obj = 0.0f;
    if (win >= 0) {
        const float* box = true_object + ((size_t)b * Mm + win) * 4;  // L2-resident
        const float ttx = box[0], tty = box[1], ttw = box[2], tth = box[3];
        const float inter = fminf(ttw, aw) * fminf(tth, ah);
        const float uni   = ttw * tth + aw * ah - inter;
        const float iou   = inter / uni;
        if (iou > IOU_THR) {
            obj = 1.0f;
            // obj_loss (mean over N)
            const float dco = conf - iou;
            acc += 5.0f * 0.5f * dco * dco;
            // prior_loss (mean over 2N)
            const float np_ = (iter_num[0] < ANCHOR_TRAIN_ITERS) ? 1.0f : 0.0f;
            const float dw = ew - aw, dh = eh - ah;
            acc += np_ * 5.0f * 0.5f * (dw * dw + dh * dh) * 0.5f;
            // true_loss (mean over 4N)
            const float d0 = px - ttx, d1 = py - tty, d2 = ew - ttw, d3 = eh - tth;
            acc += 5.0f * 0.5f * (d0 * d0 + d1 * d1 + d2 * d2 + d3 * d3) * 0.25f;
            // score_loss (mean over C*N) — sparse float4 reads
            const float4* cs4 = reinterpret_cast<const float4*>(cls_score + (size_t)gidx * Cc);
            const float4* tl4 = reinterpret_cast<const float4*>(true_label + ((size_t)b * Mm + win) * Cc);
            float ssum = 0.0f;
            #pragma unroll
            for (int c = 0; c < Cc / 4; ++c) {
                const float4 cv = cs4[c];
                const float4 tv = tl4[c];
                const float e0 = cv.x - tv.x, e1 = cv.y - tv.y;
                const float e2 = cv.z - tv.z, e3 = cv.w - tv.w;
                ssum += e0 * e0 + e1 * e1 + e2 * e2 + e3 * e3;
            }
            acc += 5.0f * 0.5f * ssum * (1.0f / (float)Cc);
        }
    }
    // noobj_loss: every cell/anchor
    acc += 0.5f * (1.0f - obj) * 0.5f * conf * conf;

    const float invN = 1.0f / ((float)Bb * (float)Ww * (float)Hh * (float)Aa);
    acc *= invN * 0.25f;   // shared divisor N; final /4

    // Block reduction: wave64 shuffle, cross-wave via LDS, one partial per block
    #pragma unroll
    for (int off = 32; off > 0; off >>= 1)
        acc += __shfl_down(acc, off, 64);
    __shared__ float s_part[4];
    if ((tid & 63) == 0) s_part[tid >> 6] = acc;
    __syncthreads();
    if (tid == 0)
        partials[blockIdx.x] = s_part[0] + s_part[1] + s_part[2] + s_part[3];
}

__launch_bounds__(256)
__global__ void reduce_kernel(const float* __restrict__ partials, float* __restrict__ out)
{
    const int tid = threadIdx.x;
    float acc = 0.0f;
    for (int i = tid; i < NBLOCKS; i += 256)
        acc += partials[i];
    #pragma unroll
    for (int off = 32; off > 0; off >>= 1)
        acc += __shfl_down(acc, off, 64);
    __shared__ float s_part[4];
    if ((tid & 63) == 0) s_part[tid >> 6] = acc;
    __syncthreads();
    if (tid == 0)
        out[0] = s_part[0] + s_part[1] + s_part[2] + s_part[3];
}

extern "C" void kernel_launch(void* const* d_in, const int* in_sizes, int n_in,
                              void* d_out, int out_size, void* d_ws, size_t ws_size,
                              hipStream_t stream) {
    const int*   iter_num    = (const int*)  d_in[0];
    const float* cls_score   = (const float*)d_in[1];
    const float* pred_object = (const float*)d_in[2];
    const float* true_label  = (const float*)d_in[3];
    const float* true_object = (const float*)d_in[4];
    const float* anchors     = (const float*)d_in[5];
    float* out      = (float*)d_out;
    float* partials = (float*)d_ws;   // 2560 floats, fully overwritten every call

    yolo_loss_kernel<<<NBLOCKS, 256, 0, stream>>>(iter_num, cls_score, pred_object,
                                                  true_label, true_object, anchors, partials);
    reduce_kernel<<<1, 256, 0, stream>>>(partials, out);
}